// Round 13
// baseline (48.730 us; speedup 1.0000x reference)
//
#include <hip/hip_runtime.h>

#define D_MODEL   2048
#define F4T       (D_MODEL / 4)        // 512 float4 per token
#define THREADS   1024                 // 16 waves
#define NWAVES    (THREADS / 64)
#define NSTRIP    8                    // D_MODEL / (64 lanes * 4 floats)
#define TOK_PER_WAVE 2
#define TOK_PER_BLOCK (NWAVES * TOK_PER_WAVE)   // 32

typedef float f4 __attribute__((ext_vector_type(4)));

// R11 base (46.9 us) with PLAIN stores instead of nontemporal.
// A/B vs R11: tests whether the NT flag costs write-path efficiency (~10%
// gap to the 6.29 TB/s copy ceiling) or was protecting x's L3 residency.
__global__ __launch_bounds__(THREADS)
void hypercube_fused_kernel(const float* __restrict__ x,
                            const float* __restrict__ W_to,
                            const float* __restrict__ W_from,
                            const float* __restrict__ log_temp,
                            const float* __restrict__ scale_p,
                            float* __restrict__ out,
                            int n_tokens)
{
    __shared__ f4    sWT[4 * F4T];        // W_to  [k][d] as f4: 32 KB
    __shared__ float sWFT[4 * D_MODEL];   // W_from^T [k][d]:    32 KB

    const int tid  = threadIdx.x;
    const int lane = tid & 63;
    const int wave = tid >> 6;

    const f4* __restrict__ X4  = reinterpret_cast<const f4*>(x);
    const f4* __restrict__ WT4 = reinterpret_cast<const f4*>(W_to);
    const f4* __restrict__ WF4 = reinterpret_cast<const f4*>(W_from);
    f4* __restrict__ O4 = reinterpret_cast<f4*>(out);

    // ---- stage W_to (copy) and W_from (transpose) into LDS ----
#pragma unroll
    for (int j = 0; j < 2; ++j)
        sWT[tid + j * THREADS] = WT4[tid + j * THREADS];
#pragma unroll
    for (int j = 0; j < 2; ++j) {
        const int d = tid + j * THREADS;          // row of W_from
        const f4 w = WF4[d];                      // [k0..k3]
        sWFT[0 * D_MODEL + d] = w.x;              // bank = d%32: conflict-free
        sWFT[1 * D_MODEL + d] = w.y;
        sWFT[2 * D_MODEL + d] = w.z;
        sWFT[3 * D_MODEL + d] = w.w;
    }
    __syncthreads();

    const f4* __restrict__ sWFT4 = reinterpret_cast<const f4*>(sWFT);

    // ---- scalars ----
    float temp = __expf(log_temp[0]);
    temp = fminf(fmaxf(temp, 0.01f), 5.0f);
    const float inv_temp = 1.0f / temp;
    const float scale = scale_p[0];

    const int tok0 = blockIdx.x * TOK_PER_BLOCK + wave * TOK_PER_WAVE;

    f4 xA[NSTRIP], xB[NSTRIP];

    // prologue: load token 0 x (8 independent dwordx4)
    {
        const size_t xb = (size_t)tok0 * F4T;
#pragma unroll
        for (int s = 0; s < NSTRIP; ++s)
            xA[s] = X4[xb + s * 64 + lane];
    }

#pragma unroll
    for (int i = 0; i < TOK_PER_WAVE; ++i) {
        f4 (&cur)[NSTRIP] = (i & 1) ? xB : xA;
        f4 (&nxt)[NSTRIP] = (i & 1) ? xA : xB;

        // ---- prefetch next token's x (independent, overlaps compute) ----
        if (i < TOK_PER_WAVE - 1) {
            const size_t xbn = (size_t)(tok0 + i + 1) * F4T;
#pragma unroll
            for (int s = 0; s < NSTRIP; ++s)
                nxt[s] = X4[xbn + s * 64 + lane];
        }

        // ---- phase 1: z[k] = sum_d x*W_to[k], W_to from LDS ----
        float z[4] = {0.f, 0.f, 0.f, 0.f};
#pragma unroll
        for (int s = 0; s < NSTRIP; ++s) {
            const int fi = s * 64 + lane;
            const f4 w0 = sWT[0*512 + fi];
            const f4 w1 = sWT[1*512 + fi];
            const f4 w2 = sWT[2*512 + fi];
            const f4 w3 = sWT[3*512 + fi];
            const f4 a  = cur[s];
            z[0] += a.x*w0.x + a.y*w0.y + a.z*w0.z + a.w*w0.w;
            z[1] += a.x*w1.x + a.y*w1.y + a.z*w1.z + a.w*w1.w;
            z[2] += a.x*w2.x + a.y*w2.y + a.z*w2.z + a.w*w2.w;
            z[3] += a.x*w3.x + a.y*w3.y + a.z*w3.z + a.w*w3.w;
        }

        // ---- wave64 butterfly reduce (4 sums) ----
#pragma unroll
        for (int off = 32; off >= 1; off >>= 1) {
#pragma unroll
            for (int k = 0; k < 4; ++k)
                z[k] += __shfl_xor(z[k], off);
        }

        // ---- lane-parallel softmax: lane owns vertex (lane&15) ----
        const int v = lane & 15;
        float ssum = 0.f;
#pragma unroll
        for (int j = 0; j < 4; ++j) {
            const float dz = z[j] - (float)((v >> j) & 1);
            ssum += dz * dz;
        }
        const float e = __expf(-__builtin_amdgcn_sqrtf(ssum) * inv_temp);
        float s0 = e;
        float s1 = ((v >> 0) & 1) ? e : 0.f;
        float s2 = ((v >> 1) & 1) ? e : 0.f;
        float s3 = ((v >> 2) & 1) ? e : 0.f;
        float s4 = ((v >> 3) & 1) ? e : 0.f;
#pragma unroll
        for (int off = 8; off >= 1; off >>= 1) {
            s0 += __shfl_xor(s0, off);
            s1 += __shfl_xor(s1, off);
            s2 += __shfl_xor(s2, off);
            s3 += __shfl_xor(s3, off);
            s4 += __shfl_xor(s4, off);
        }
        const float qs = scale * __builtin_amdgcn_rcpf(s0);
        const float q0 = s1*qs, q1 = s2*qs, q2 = s3*qs, q3 = s4*qs;

        // ---- phase 2: out = x + sum_k q[k]*WFT[k][d], PLAIN stores ----
        const size_t xb = (size_t)(tok0 + i) * F4T;
#pragma unroll
        for (int s = 0; s < NSTRIP; ++s) {
            const int fi = s * 64 + lane;
            const f4 wk0 = sWFT4[0*512 + fi];
            const f4 wk1 = sWFT4[1*512 + fi];
            const f4 wk2 = sWFT4[2*512 + fi];
            const f4 wk3 = sWFT4[3*512 + fi];
            f4 o = cur[s] + q0*wk0 + q1*wk1 + q2*wk2 + q3*wk3;
            O4[xb + fi] = o;
        }
    }
}

extern "C" void kernel_launch(void* const* d_in, const int* in_sizes, int n_in,
                              void* d_out, int out_size, void* d_ws, size_t ws_size,
                              hipStream_t stream) {
    const float* x        = (const float*)d_in[0];
    const float* W_to     = (const float*)d_in[1];
    const float* W_from   = (const float*)d_in[2];
    const float* log_temp = (const float*)d_in[3];
    const float* scale    = (const float*)d_in[4];
    float* out = (float*)d_out;

    const int n_tokens = in_sizes[0] / D_MODEL;      // 16384
    const int blocks = (n_tokens + TOK_PER_BLOCK - 1) / TOK_PER_BLOCK;  // 512
    hypercube_fused_kernel<<<blocks, THREADS, 0, stream>>>(
        x, W_to, W_from, log_temp, scale, out, n_tokens);
}

// Round 14
// 46.635 us; speedup vs baseline: 1.0449x; 1.0449x over previous
//
#include <hip/hip_runtime.h>

#define D_MODEL   2048
#define F4T       (D_MODEL / 4)        // 512 float4 per token
#define THREADS   1024                 // 16 waves
#define NWAVES    (THREADS / 64)
#define NSTRIP    8                    // D_MODEL / (64 lanes * 4 floats)
#define TOK_PER_WAVE 2
#define TOK_PER_BLOCK (NWAVES * TOK_PER_WAVE)   // 32

typedef float f4 __attribute__((ext_vector_type(4)));

// FINAL (R11 restore, 46.9 us measured): fused single-pass kernel.
//  - x read from HBM exactly once, held in VGPRs (no spill: VGPR 44)
//  - W_to/W_from LDS-staged per block (64 KB), W_from transposed [k][d]
//    so phase-2 reads are unit-stride ds_read_b128, 0 bank conflicts
//  - tall blocks: 1024 thr + 64 KB LDS -> 2 blocks/CU = 8 waves/SIMD
//  - ping-pong x prefetch across the 2 tokens/wave
//  - lane-parallel softmax (lane owns vertex lane&15; 16-lane butterfly);
//    dist>=0 => exp in (0,1], max-subtraction provably unnecessary
//  - hw transcendentals (v_exp/v_sqrt/v_rcp): validated absmax 0.0156
//  - nontemporal out stores (A/B'd vs plain: NT wins, protects x L3 residency)
// Roofline: 268 MB logical @ 46.9 us = 5.7 TB/s = 91% of measured 6.29 TB/s
// copy ceiling. Occupancy x2, DS-pipe /2.4, store-flavor A/Bs all flat.
__global__ __launch_bounds__(THREADS)
void hypercube_fused_kernel(const float* __restrict__ x,
                            const float* __restrict__ W_to,
                            const float* __restrict__ W_from,
                            const float* __restrict__ log_temp,
                            const float* __restrict__ scale_p,
                            float* __restrict__ out,
                            int n_tokens)
{
    __shared__ f4    sWT[4 * F4T];        // W_to  [k][d] as f4: 32 KB
    __shared__ float sWFT[4 * D_MODEL];   // W_from^T [k][d]:    32 KB

    const int tid  = threadIdx.x;
    const int lane = tid & 63;
    const int wave = tid >> 6;

    const f4* __restrict__ X4  = reinterpret_cast<const f4*>(x);
    const f4* __restrict__ WT4 = reinterpret_cast<const f4*>(W_to);
    const f4* __restrict__ WF4 = reinterpret_cast<const f4*>(W_from);
    f4* __restrict__ O4 = reinterpret_cast<f4*>(out);

    // ---- stage W_to (copy) and W_from (transpose) into LDS ----
#pragma unroll
    for (int j = 0; j < 2; ++j)
        sWT[tid + j * THREADS] = WT4[tid + j * THREADS];
#pragma unroll
    for (int j = 0; j < 2; ++j) {
        const int d = tid + j * THREADS;          // row of W_from
        const f4 w = WF4[d];                      // [k0..k3]
        sWFT[0 * D_MODEL + d] = w.x;              // bank = d%32: conflict-free
        sWFT[1 * D_MODEL + d] = w.y;
        sWFT[2 * D_MODEL + d] = w.z;
        sWFT[3 * D_MODEL + d] = w.w;
    }
    __syncthreads();

    const f4* __restrict__ sWFT4 = reinterpret_cast<const f4*>(sWFT);

    // ---- scalars ----
    float temp = __expf(log_temp[0]);
    temp = fminf(fmaxf(temp, 0.01f), 5.0f);
    const float inv_temp = 1.0f / temp;
    const float scale = scale_p[0];

    const int tok0 = blockIdx.x * TOK_PER_BLOCK + wave * TOK_PER_WAVE;

    f4 xA[NSTRIP], xB[NSTRIP];

    // prologue: load token 0 x (8 independent dwordx4)
    {
        const size_t xb = (size_t)tok0 * F4T;
#pragma unroll
        for (int s = 0; s < NSTRIP; ++s)
            xA[s] = X4[xb + s * 64 + lane];
    }

#pragma unroll
    for (int i = 0; i < TOK_PER_WAVE; ++i) {
        f4 (&cur)[NSTRIP] = (i & 1) ? xB : xA;
        f4 (&nxt)[NSTRIP] = (i & 1) ? xA : xB;

        // ---- prefetch next token's x (independent, overlaps compute) ----
        if (i < TOK_PER_WAVE - 1) {
            const size_t xbn = (size_t)(tok0 + i + 1) * F4T;
#pragma unroll
            for (int s = 0; s < NSTRIP; ++s)
                nxt[s] = X4[xbn + s * 64 + lane];
        }

        // ---- phase 1: z[k] = sum_d x*W_to[k], W_to from LDS ----
        float z[4] = {0.f, 0.f, 0.f, 0.f};
#pragma unroll
        for (int s = 0; s < NSTRIP; ++s) {
            const int fi = s * 64 + lane;
            const f4 w0 = sWT[0*512 + fi];
            const f4 w1 = sWT[1*512 + fi];
            const f4 w2 = sWT[2*512 + fi];
            const f4 w3 = sWT[3*512 + fi];
            const f4 a  = cur[s];
            z[0] += a.x*w0.x + a.y*w0.y + a.z*w0.z + a.w*w0.w;
            z[1] += a.x*w1.x + a.y*w1.y + a.z*w1.z + a.w*w1.w;
            z[2] += a.x*w2.x + a.y*w2.y + a.z*w2.z + a.w*w2.w;
            z[3] += a.x*w3.x + a.y*w3.y + a.z*w3.z + a.w*w3.w;
        }

        // ---- wave64 butterfly reduce (4 sums) ----
#pragma unroll
        for (int off = 32; off >= 1; off >>= 1) {
#pragma unroll
            for (int k = 0; k < 4; ++k)
                z[k] += __shfl_xor(z[k], off);
        }

        // ---- lane-parallel softmax: lane owns vertex (lane&15) ----
        const int v = lane & 15;
        float ssum = 0.f;
#pragma unroll
        for (int j = 0; j < 4; ++j) {
            const float dz = z[j] - (float)((v >> j) & 1);
            ssum += dz * dz;
        }
        const float e = __expf(-__builtin_amdgcn_sqrtf(ssum) * inv_temp);
        float s0 = e;
        float s1 = ((v >> 0) & 1) ? e : 0.f;
        float s2 = ((v >> 1) & 1) ? e : 0.f;
        float s3 = ((v >> 2) & 1) ? e : 0.f;
        float s4 = ((v >> 3) & 1) ? e : 0.f;
#pragma unroll
        for (int off = 8; off >= 1; off >>= 1) {
            s0 += __shfl_xor(s0, off);
            s1 += __shfl_xor(s1, off);
            s2 += __shfl_xor(s2, off);
            s3 += __shfl_xor(s3, off);
            s4 += __shfl_xor(s4, off);
        }
        const float qs = scale * __builtin_amdgcn_rcpf(s0);
        const float q0 = s1*qs, q1 = s2*qs, q2 = s3*qs, q3 = s4*qs;

        // ---- phase 2: out = x + sum_k q[k]*WFT[k][d], WFT from LDS ----
        const size_t xb = (size_t)(tok0 + i) * F4T;
#pragma unroll
        for (int s = 0; s < NSTRIP; ++s) {
            const int fi = s * 64 + lane;
            const f4 wk0 = sWFT4[0*512 + fi];
            const f4 wk1 = sWFT4[1*512 + fi];
            const f4 wk2 = sWFT4[2*512 + fi];
            const f4 wk3 = sWFT4[3*512 + fi];
            f4 o = cur[s] + q0*wk0 + q1*wk1 + q2*wk2 + q3*wk3;
            __builtin_nontemporal_store(o, &O4[xb + fi]);
        }
    }
}

extern "C" void kernel_launch(void* const* d_in, const int* in_sizes, int n_in,
                              void* d_out, int out_size, void* d_ws, size_t ws_size,
                              hipStream_t stream) {
    const float* x        = (const float*)d_in[0];
    const float* W_to     = (const float*)d_in[1];
    const float* W_from   = (const float*)d_in[2];
    const float* log_temp = (const float*)d_in[3];
    const float* scale    = (const float*)d_in[4];
    float* out = (float*)d_out;

    const int n_tokens = in_sizes[0] / D_MODEL;      // 16384
    const int blocks = (n_tokens + TOK_PER_BLOCK - 1) / TOK_PER_BLOCK;  // 512
    hypercube_fused_kernel<<<blocks, THREADS, 0, stream>>>(
        x, W_to, W_from, log_temp, scale, out, n_tokens);
}